// Round 7
// baseline (79.844 us; speedup 1.0000x reference)
//
#include <hip/hip_runtime.h>
#include <hip/hip_bf16.h>

#define B_   32
#define L_   2048
#define DIN  384
#define DH   64
#define DOUT 64
#define CS   32      // chunk length
#define NC   64      // chunks per sequence
#define WN   192     // Z row: shorts [0..127]=(re,im) pairs h=0..63; [128..159]=Du col c; [160..191]=Du col 32+c

typedef __attribute__((ext_vector_type(8)))  short short8;
typedef __attribute__((ext_vector_type(4)))  float f32x4;
typedef __attribute__((ext_vector_type(16))) float f32x16;

__device__ __forceinline__ float bf2f(short s) {
  union { unsigned u; float f; } cv;
  cv.u = ((unsigned)(unsigned short)s) << 16;
  return cv.f;
}
__device__ __forceinline__ short f2bf(float f) {
  __hip_bfloat16 h = __float2bfloat16(f);
  union { __hip_bfloat16 h; short s; } cv; cv.h = h;
  return cv.s;
}
__device__ __forceinline__ unsigned pack2(float lo, float hi) {
  return (unsigned)(unsigned short)f2bf(lo) | ((unsigned)(unsigned short)f2bf(hi) << 16);
}

// ---------------- K0: pack Wp (B-frag order), Ctp (proj B-frag order), lamtab ----
__global__ void k0_prep(const float* __restrict__ nu_log, const float* __restrict__ theta_log,
                        const float* __restrict__ gamma_log,
                        const float* __restrict__ B_re, const float* __restrict__ B_im,
                        const float* __restrict__ C_re, const float* __restrict__ C_im,
                        const float* __restrict__ Dm,
                        short* __restrict__ Wp, short* __restrict__ Ctp,
                        float* __restrict__ lamtab) {
  int tid = blockIdx.x * 256 + threadIdx.x;
  // Wp[((nt*24+ks)*64+l)*8+j] = W[nt*32+(l&31)][ks*16+(l>>5)*8+j]
  for (int q = tid; q < 6 * 24 * 64; q += gridDim.x * 256) {
    int l = q & 63, ks = (q >> 6) % 24, nt = q / (24 * 64);
    int n = nt * 32 + (l & 31);
    int k0 = ks * 16 + ((l >> 5) << 3);
    short8 v;
    #pragma unroll
    for (int j = 0; j < 8; ++j) {
      int k = k0 + j;
      float x;
      if (n < 64)       x = B_re[n * DIN + k] * expf(gamma_log[n]);
      else if (n < 128) x = B_im[(n - 64) * DIN + k] * expf(gamma_log[n - 64]);
      else              x = Dm[(n - 128) * DIN + k];
      v[j] = f2bf(x);
    }
    *(short8*)(Wp + (size_t)q * 8) = v;
  }
  // Ctp[((nt2*8+ks2)*64+l)*8+j]: B[k][o], k<64 -> C_re[o][k], k>=64 -> -C_im[o][k-64]
  for (int q = tid; q < 2 * 8 * 64; q += gridDim.x * 256) {
    int l = q & 63, ks2 = (q >> 6) & 7, nt2 = q >> 9;
    int o = nt2 * 32 + (l & 31);
    int kk0 = ks2 * 16 + ((l >> 5) << 3);
    short8 v;
    #pragma unroll
    for (int j = 0; j < 8; ++j) {
      int k = kk0 + j;
      float x = (k < 64) ? C_re[o * DH + k] : -C_im[o * DH + (k - 64)];
      v[j] = f2bf(x);
    }
    *(short8*)(Ctp + (size_t)q * 8) = v;
  }
  if (blockIdx.x == 0 && threadIdx.x < 64) {
    int h = threadIdx.x;
    float nu = expf(nu_log[h]);
    float th = expf(theta_log[h]);
    float rr = expf(-nu);
    float lr = rr * cosf(th), li = rr * sinf(th);
    float ar = lr, ai = li;
    #pragma unroll
    for (int q = 0; q < 5; ++q) { float nr = ar * ar - ai * ai; ai = 2.f * ar * ai; ar = nr; }
    lamtab[h] = lr; lamtab[64 + h] = li;        // lambda
    lamtab[128 + h] = ar; lamtab[192 + h] = ai; // lambda^32
  }
}

// ---- K1: 6 waves per 32-row chunk; wave w owns N-panel nt=w with its WHOLE B panel
//      in registers (24x short8, loaded in one burst). K-loop = LDS A + MFMA only.
//      Waves 0/1: re (h=0..31 / 32..63) + scan; waves 2/3: im (exported via LDS);
//      waves 4/5: Du. ----
__global__ __launch_bounds__(384, 3) void k1_gemm_scan(const float* __restrict__ X,
                                                       const short* __restrict__ Wp,
                                                       const float* __restrict__ lamtab,
                                                       short* __restrict__ Z,
                                                       float* __restrict__ E) {
  __shared__ short Xs[32 * 384];                 // 24 KB, XOR-swizzled on 8-elem units
  __shared__ float ldsim[2][32][32];             // 8 KB: im panels from waves 2/3
  const int t = threadIdx.x, w = t >> 6, lane = t & 63;
  const int c = lane & 31, kh = lane >> 5;
  const int m0 = blockIdx.x * 32;

  // ---- A global loads FIRST (so their wait leaves B loads in flight)
  // 1536 8-float units total; each thread loads 4 contiguous units (12 thr/row)
  const int r = t / 12, u0 = (t % 12) * 4;
  const float* src = X + (size_t)(m0 + r) * DIN + u0 * 8;
  f32x4 g0a = *(const f32x4*)(src);
  f32x4 g0b = *(const f32x4*)(src + 4);
  f32x4 g1a = *(const f32x4*)(src + 8);
  f32x4 g1b = *(const f32x4*)(src + 12);
  f32x4 g2a = *(const f32x4*)(src + 16);
  f32x4 g2b = *(const f32x4*)(src + 20);
  f32x4 g3a = *(const f32x4*)(src + 24);
  f32x4 g3b = *(const f32x4*)(src + 28);

  // ---- B panel burst: 24 independent loads, all in flight together
  const short* wq = Wp + (size_t)w * 12288 + lane * 8;
  short8 b0,b1,b2,b3,b4,b5,b6,b7,b8,b9,b10,b11,b12,b13,b14,b15,b16,b17,b18,b19,b20,b21,b22,b23;
#define LOADB(i) b##i = *(const short8*)(wq + (i) * 512)
  LOADB(0);  LOADB(1);  LOADB(2);  LOADB(3);  LOADB(4);  LOADB(5);
  LOADB(6);  LOADB(7);  LOADB(8);  LOADB(9);  LOADB(10); LOADB(11);
  LOADB(12); LOADB(13); LOADB(14); LOADB(15); LOADB(16); LOADB(17);
  LOADB(18); LOADB(19); LOADB(20); LOADB(21); LOADB(22); LOADB(23);
#undef LOADB

  // ---- convert + swizzled LDS write of A (4 units; 4-aligned block stays in one 8-group)
  {
    short8 v0, v1, v2, v3;
    #pragma unroll
    for (int i = 0; i < 4; ++i) {
      v0[i] = f2bf(g0a[i]); v0[4 + i] = f2bf(g0b[i]);
      v1[i] = f2bf(g1a[i]); v1[4 + i] = f2bf(g1b[i]);
      v2[i] = f2bf(g2a[i]); v2[4 + i] = f2bf(g2b[i]);
      v3[i] = f2bf(g3a[i]); v3[4 + i] = f2bf(g3b[i]);
    }
    int up0 = ((u0 + 0) & ~7) | (((u0 + 0) ^ r) & 7);
    int up1 = ((u0 + 1) & ~7) | (((u0 + 1) ^ r) & 7);
    int up2 = ((u0 + 2) & ~7) | (((u0 + 2) ^ r) & 7);
    int up3 = ((u0 + 3) & ~7) | (((u0 + 3) ^ r) & 7);
    *(short8*)&Xs[r * 384 + up0 * 8] = v0;
    *(short8*)&Xs[r * 384 + up1 * 8] = v1;
    *(short8*)&Xs[r * 384 + up2 * 8] = v2;
    *(short8*)&Xs[r * 384 + up3 * 8] = v3;
  }
  __syncthreads();

  // ---- K-loop: pure LDS + MFMA (B already in registers)
  const short* xrow = &Xs[c * 384];
#define AREAD(KS) (*(const short8*)&xrow[(((((KS)*2 + kh)) & ~7) | ((((KS)*2 + kh) ^ c) & 7)) * 8])
  f32x16 acc;
  #pragma unroll
  for (int j = 0; j < 16; ++j) acc[j] = 0.f;
  short8 acur = AREAD(0), anxt = AREAD(1);
#define STEP(i) { short8 an; if ((i) < 22) an = AREAD((i) + 2); \
  acc = __builtin_amdgcn_mfma_f32_32x32x16_bf16(acur, b##i, acc, 0, 0, 0); \
  acur = anxt; if ((i) < 22) anxt = an; }
  STEP(0)  STEP(1)  STEP(2)  STEP(3)  STEP(4)  STEP(5)
  STEP(6)  STEP(7)  STEP(8)  STEP(9)  STEP(10) STEP(11)
  STEP(12) STEP(13) STEP(14) STEP(15) STEP(16) STEP(17)
  STEP(18) STEP(19) STEP(20) STEP(21) STEP(22) STEP(23)
#undef STEP
#undef AREAD

  // ---- waves 2/3: export im panel to LDS; waves 4/5: store Du columns
  if (w == 2 || w == 3) {
    #pragma unroll
    for (int reg = 0; reg < 16; ++reg) {
      const int row = (reg & 3) + 8 * (reg >> 2) + 4 * kh;
      ldsim[w - 2][row][c] = acc[reg];
    }
  } else if (w >= 4) {
    #pragma unroll
    for (int reg = 0; reg < 16; ++reg) {
      const int row = (reg & 3) + 8 * (reg >> 2) + 4 * kh;
      Z[(size_t)(m0 + row) * WN + 128 + (w - 4) * 32 + c] = f2bf(acc[reg]);
    }
  }
  __syncthreads();

  // ---- waves 0/1: in-register scan over the 32 rows (h = w*32 + c), store pairs + E
  if (w < 2) {
    const float lr = lamtab[w * 32 + c], li = lamtab[64 + w * 32 + c];
    float sr = 0.f, si = 0.f;
    #pragma unroll
    for (int g = 0; g < 8; ++g) {
      const int active = (g & 1);
      if (kh == active) {
        #pragma unroll
        for (int j = 0; j < 4; ++j) {
          const int rg = 4 * (g >> 1) + j;
          const int row = 4 * g + j;
          float im_in = ldsim[w][row][c];
          float nr = lr * sr - li * si + acc[rg];
          si = lr * si + li * sr + im_in;
          sr = nr;
          *(unsigned*)(Z + (size_t)(m0 + row) * WN + w * 64 + 2 * c) = pack2(sr, si);
        }
      }
      float tr = __shfl_xor(sr, 32), ti = __shfl_xor(si, 32);
      if (kh != active) { sr = tr; si = ti; }
    }
    if (kh == 0) {
      float* Ep = E + (size_t)blockIdx.x * 128;
      Ep[w * 32 + c] = sr;
      Ep[64 + w * 32 + c] = si;
    }
  }
}

// ---- K4: carry + correction + MFMA projection + Du + chunk max (no barriers) ----
__global__ __launch_bounds__(256, 4) void k4_scanproj(const short* __restrict__ Z,
                                                      const float* __restrict__ lamtab,
                                                      const float* __restrict__ E,
                                                      const short* __restrict__ Ctp,
                                                      float* __restrict__ P) {
  const int t = threadIdx.x, w = t >> 6, lane = t & 63;
  const int b = blockIdx.x >> 4, cg = blockIdx.x & 15;
  const int c = cg * 4 + w;                      // this wave's chunk
  __shared__ short xsA[4][CS * 128];             // 32 KB, swizzled A-frag layout
  const size_t zrow0 = (size_t)(b * L_ + c * CS) * WN;

  // carry over previous chunks (lane = h)
  const int h = lane;
  const float Lr = lamtab[128 + h], Li = lamtab[192 + h];
  const float lr = lamtab[h],       li = lamtab[64 + h];
  float cr = 0.f, ci = 0.f;
  const float* Eb = E + (size_t)b * NC * 128;
  for (int cp = 0; cp < c; ++cp) {
    float er = Eb[cp * 128 + h], ei = Eb[cp * 128 + 64 + h];
    float nr = Lr * cr - Li * ci + er;
    ci = Lr * ci + Li * cr + ei;
    cr = nr;
  }
  // correction: xs[l][h] = loc[l][h] + lam^{l+1} * carry ; write bf16 A-frag LDS
  {
    float wr2 = cr, wi2 = ci;
    short* xa = &xsA[w][0];
    const int ure = h >> 3, uim = 8 + (h >> 3), ho = h & 7;
    #pragma unroll 8
    for (int l = 0; l < CS; ++l) {
      float nr = lr * wr2 - li * wi2;
      wi2 = lr * wi2 + li * wr2;
      wr2 = nr;
      unsigned pr = *(const unsigned*)(Z + zrow0 + (size_t)l * WN + 2 * h);
      float xr = bf2f((short)(pr & 0xffff)) + wr2;
      float xi = bf2f((short)(pr >> 16))    + wi2;
      int l7 = l & 7;
      xa[l * 128 + ((ure & ~7) | ((ure ^ l7) & 7)) * 8 + ho] = f2bf(xr);
      xa[l * 128 + ((uim & ~7) | ((uim ^ l7) & 7)) * 8 + ho] = f2bf(xi);
    }
  }

  // MFMA projection: y(32x64) = [xs_re|xs_im](32x128) @ Ctp(128x64)
  const int cc = lane & 31, kh = lane >> 5;
  f32x16 y0, y1;
  #pragma unroll
  for (int j = 0; j < 16; ++j) { y0[j] = 0.f; y1[j] = 0.f; }
  #pragma unroll
  for (int ks = 0; ks < 8; ++ks) {
    int u = ks * 2 + kh;
    int up = (u & ~7) | ((u ^ (cc & 7)) & 7);
    short8 af = *(const short8*)&xsA[w][cc * 128 + up * 8];
    short8 g0 = *(const short8*)(Ctp + ((size_t)((0 * 8 + ks) * 64 + lane)) * 8);
    short8 g1 = *(const short8*)(Ctp + ((size_t)((1 * 8 + ks) * 64 + lane)) * 8);
    y0 = __builtin_amdgcn_mfma_f32_32x32x16_bf16(af, g0, y0, 0, 0, 0);
    y1 = __builtin_amdgcn_mfma_f32_32x32x16_bf16(af, g1, y1, 0, 0, 0);
  }
  // Du add + max over rows
  float mv0 = -3.4e38f, mv1 = -3.4e38f;
  #pragma unroll
  for (int reg = 0; reg < 16; ++reg) {
    const int row = (reg & 3) + 8 * (reg >> 2) + 4 * kh;
    float d0 = bf2f(Z[zrow0 + (size_t)row * WN + 128 + cc]);
    float d1 = bf2f(Z[zrow0 + (size_t)row * WN + 160 + cc]);
    mv0 = fmaxf(mv0, y0[reg] + d0);
    mv1 = fmaxf(mv1, y1[reg] + d1);
  }
  mv0 = fmaxf(mv0, __shfl_xor(mv0, 32));
  mv1 = fmaxf(mv1, __shfl_xor(mv1, 32));
  if (kh == 0) {
    float* Pp = P + ((size_t)b * NC + c) * 64;
    Pp[cc] = mv0;
    Pp[32 + cc] = mv1;
  }
}

// ---------------- K5: max over chunks ----------------
__global__ void k5_reduce(const float* __restrict__ P, float* __restrict__ out) {
  int idx = blockIdx.x * 256 + threadIdx.x;      // = b*64 + o
  int b = idx >> 6, o = idx & 63;
  float m = -3.4e38f;
  for (int c = 0; c < NC; ++c) m = fmaxf(m, P[((size_t)b * NC + c) * 64 + o]);
  out[idx] = m;
}

extern "C" void kernel_launch(void* const* d_in, const int* in_sizes, int n_in,
                              void* d_out, int out_size, void* d_ws, size_t ws_size,
                              hipStream_t stream) {
  const float* X         = (const float*)d_in[0];
  const float* nu_log    = (const float*)d_in[1];
  const float* theta_log = (const float*)d_in[2];
  const float* gamma_log = (const float*)d_in[3];
  const float* B_re      = (const float*)d_in[4];
  const float* B_im      = (const float*)d_in[5];
  const float* C_re      = (const float*)d_in[6];
  const float* C_im      = (const float*)d_in[7];
  const float* Dm        = (const float*)d_in[8];
  float* out = (float*)d_out;

  char* ws = (char*)d_ws;
  short* Wp     = (short*)ws;                       // 147456 B
  short* Ctp    = (short*)(ws + 147456);            // 16384 B
  float* lamtab = (float*)(ws + 163840);            // 1024 B
  short* Z      = (short*)(ws + 165888);            // 25165824 B
  float* E      = (float*)(ws + 165888 + 25165824); // 1048576 B
  float* P      = (float*)(ws + 165888 + 25165824 + 1048576); // 524288 B

  k0_prep<<<64, 256, 0, stream>>>(nu_log, theta_log, gamma_log, B_re, B_im,
                                  C_re, C_im, Dm, Wp, Ctp, lamtab);
  k1_gemm_scan<<<2048, 384, 0, stream>>>(X, Wp, lamtab, Z, E);
  k4_scanproj<<<512, 256, 0, stream>>>(Z, lamtab, E, Ctp, P);
  k5_reduce<<<8, 256, 0, stream>>>(P, out);
}

// Round 8
// 76.554 us; speedup vs baseline: 1.0430x; 1.0430x over previous
//
#include <hip/hip_runtime.h>
#include <hip/hip_bf16.h>

#define B_   32
#define L_   2048
#define DIN  384
#define DH   64
#define DOUT 64
#define CS   32      // chunk length
#define NC   64      // chunks per sequence
#define WN   192     // Z row: shorts [0..127]=(re,im) pairs h=0..63; [128..159]=Du col c; [160..191]=Du col 32+c

typedef __attribute__((ext_vector_type(8)))  short short8;
typedef __attribute__((ext_vector_type(4)))  float f32x4;
typedef __attribute__((ext_vector_type(16))) float f32x16;

__device__ __forceinline__ float bf2f(short s) {
  union { unsigned u; float f; } cv;
  cv.u = ((unsigned)(unsigned short)s) << 16;
  return cv.f;
}
__device__ __forceinline__ short f2bf(float f) {
  __hip_bfloat16 h = __float2bfloat16(f);
  union { __hip_bfloat16 h; short s; } cv; cv.h = h;
  return cv.s;
}
__device__ __forceinline__ unsigned pack2(float lo, float hi) {
  return (unsigned)(unsigned short)f2bf(lo) | ((unsigned)(unsigned short)f2bf(hi) << 16);
}
__device__ __forceinline__ void gll16(const float* g, float* l) {
  __builtin_amdgcn_global_load_lds((const __attribute__((address_space(1))) unsigned int*)g,
                                   (__attribute__((address_space(3))) unsigned int*)l, 16, 0, 0);
}

// ---------------- K0: pack Wp (B-frag order), Ctp (proj B-frag order), lamtab ----
__global__ void k0_prep(const float* __restrict__ nu_log, const float* __restrict__ theta_log,
                        const float* __restrict__ gamma_log,
                        const float* __restrict__ B_re, const float* __restrict__ B_im,
                        const float* __restrict__ C_re, const float* __restrict__ C_im,
                        const float* __restrict__ Dm,
                        short* __restrict__ Wp, short* __restrict__ Ctp,
                        float* __restrict__ lamtab) {
  int tid = blockIdx.x * 256 + threadIdx.x;
  // Wp[((nt*24+ks)*64+l)*8+j] = W[nt*32+(l&31)][ks*16+(l>>5)*8+j]
  for (int q = tid; q < 6 * 24 * 64; q += gridDim.x * 256) {
    int l = q & 63, ks = (q >> 6) % 24, nt = q / (24 * 64);
    int n = nt * 32 + (l & 31);
    int k0 = ks * 16 + ((l >> 5) << 3);
    short8 v;
    #pragma unroll
    for (int j = 0; j < 8; ++j) {
      int k = k0 + j;
      float x;
      if (n < 64)       x = B_re[n * DIN + k] * expf(gamma_log[n]);
      else if (n < 128) x = B_im[(n - 64) * DIN + k] * expf(gamma_log[n - 64]);
      else              x = Dm[(n - 128) * DIN + k];
      v[j] = f2bf(x);
    }
    *(short8*)(Wp + (size_t)q * 8) = v;
  }
  // Ctp[((nt2*8+ks2)*64+l)*8+j]: B[k][o], k<64 -> C_re[o][k], k>=64 -> -C_im[o][k-64]
  for (int q = tid; q < 2 * 8 * 64; q += gridDim.x * 256) {
    int l = q & 63, ks2 = (q >> 6) & 7, nt2 = q >> 9;
    int o = nt2 * 32 + (l & 31);
    int kk0 = ks2 * 16 + ((l >> 5) << 3);
    short8 v;
    #pragma unroll
    for (int j = 0; j < 8; ++j) {
      int k = kk0 + j;
      float x = (k < 64) ? C_re[o * DH + k] : -C_im[o * DH + (k - 64)];
      v[j] = f2bf(x);
    }
    *(short8*)(Ctp + (size_t)q * 8) = v;
  }
  if (blockIdx.x == 0 && threadIdx.x < 64) {
    int h = threadIdx.x;
    float nu = expf(nu_log[h]);
    float th = expf(theta_log[h]);
    float rr = expf(-nu);
    float lr = rr * cosf(th), li = rr * sinf(th);
    float ar = lr, ai = li;
    #pragma unroll
    for (int q = 0; q < 5; ++q) { float nr = ar * ar - ai * ai; ai = 2.f * ar * ai; ar = nr; }
    lamtab[h] = lr; lamtab[64 + h] = li;        // lambda
    lamtab[128 + h] = ar; lamtab[192 + h] = ai; // lambda^32
  }
}

// A-fragment read from fp32 LDS half-tile (48 units/row, XOR-swizzled), cvt to bf16
__device__ __forceinline__ short8 afrag(const float* buf, int ks12, int c, int kh) {
  int u = ks12 * 4 + kh * 2;
  int s0 = (u & ~7) | ((u ^ c) & 7);
  int s1 = ((u + 1) & ~7) | (((u + 1) ^ c) & 7);
  f32x4 lo = *(const f32x4*)(buf + (c * 48 + s0) * 4);
  f32x4 hi = *(const f32x4*)(buf + (c * 48 + s1) * 4);
  short8 af;
  #pragma unroll
  for (int i = 0; i < 4; ++i) { af[i] = f2bf(lo[i]); af[4 + i] = f2bf(hi[i]); }
  return af;
}

// ---- K1: 512 blocks x 6 waves; block owns 128 rows (4 chunks). B panels in regs
//      (loaded once per block); A streamed fp32 global->LDS via global_load_lds,
//      double-buffered 24KB half-K tiles. Waves 0/1: re + scan; 2/3: im (via LDS);
//      4/5: Du. ----
__global__ __launch_bounds__(384, 2) void k1_gemm_scan(const float* __restrict__ X,
                                                       const short* __restrict__ Wp,
                                                       const float* __restrict__ lamtab,
                                                       short* __restrict__ Z,
                                                       float* __restrict__ E) {
  __shared__ float Abuf[2][6144];                // 2 x 24 KB fp32 half-K tiles
  __shared__ float ldsim[2][32][32];             // 8 KB: im panels from waves 2/3
  const int t = threadIdx.x, w = t >> 6, lane = t & 63;
  const int c = lane & 31, kh = lane >> 5;
  const int row0 = blockIdx.x * 128;

  // ---- B panel burst: 24 loads, once per block, pinned in VGPRs
  const short* wq = Wp + (size_t)w * 12288 + lane * 8;
  short8 b0,b1,b2,b3,b4,b5,b6,b7,b8,b9,b10,b11,b12,b13,b14,b15,b16,b17,b18,b19,b20,b21,b22,b23;
#define LOADB(i) b##i = *(const short8*)(wq + (i) * 512)
  LOADB(0);  LOADB(1);  LOADB(2);  LOADB(3);  LOADB(4);  LOADB(5);
  LOADB(6);  LOADB(7);  LOADB(8);  LOADB(9);  LOADB(10); LOADB(11);
  LOADB(12); LOADB(13); LOADB(14); LOADB(15); LOADB(16); LOADB(17);
  LOADB(18); LOADB(19); LOADB(20); LOADB(21); LOADB(22); LOADB(23);
#undef LOADB
  asm volatile("" : "+v"(b0),"+v"(b1),"+v"(b2),"+v"(b3),"+v"(b4),"+v"(b5),
                    "+v"(b6),"+v"(b7),"+v"(b8),"+v"(b9),"+v"(b10),"+v"(b11));
  asm volatile("" : "+v"(b12),"+v"(b13),"+v"(b14),"+v"(b15),"+v"(b16),"+v"(b17),
                    "+v"(b18),"+v"(b19),"+v"(b20),"+v"(b21),"+v"(b22),"+v"(b23));

  // ---- staging geometry: 1536 16B-units per half-tile; thread covers q = i*384+w*64+lane
  int so0, so1, so2, so3;                         // source float offsets (swizzled)
  {
    int q0 = w * 64 + lane;
    #define MKSO(i, dst) { int q = q0 + (i) * 384; int r = q / 48, s = q - r * 48; \
      int p = (s & ~7) | ((s ^ r) & 7); dst = r * DIN + p * 4; }
    MKSO(0, so0) MKSO(1, so1) MKSO(2, so2) MKSO(3, so3)
    #undef MKSO
  }
#define ISSUE(CH, HF) { const float* sb = X + (size_t)(row0 + (CH) * 32) * DIN + (HF) * 192; \
    float* db = &Abuf[HF][(size_t)w * 256]; \
    gll16(sb + so0, db);          gll16(sb + so1, db + 1536); \
    gll16(sb + so2, db + 3072);   gll16(sb + so3, db + 4608); }

  ISSUE(0, 0);                                    // prologue

  const float lr = lamtab[(w & 1) * 32 + c], li = lamtab[64 + (w & 1) * 32 + c];

  for (int chunk = 0; chunk < 4; ++chunk) {
    f32x16 acc;
    #pragma unroll
    for (int j = 0; j < 16; ++j) acc[j] = 0.f;

    __syncthreads();                              // half0 tile landed
    ISSUE(chunk, 1);                              // half1 in flight during half0 compute
    {
      const float* bufp = &Abuf[0][0];
#define KSTEP(K, BR) acc = __builtin_amdgcn_mfma_f32_32x32x16_bf16(afrag(bufp, K, c, kh), BR, acc, 0, 0, 0);
      KSTEP(0,b0) KSTEP(1,b1) KSTEP(2,b2)  KSTEP(3,b3)  KSTEP(4,b4)   KSTEP(5,b5)
      KSTEP(6,b6) KSTEP(7,b7) KSTEP(8,b8)  KSTEP(9,b9)  KSTEP(10,b10) KSTEP(11,b11)
    }
    __syncthreads();                              // half1 tile landed
    if (chunk < 3) ISSUE(chunk + 1, 0);           // next chunk half0 in flight
    {
      const float* bufp = &Abuf[1][0];
      KSTEP(0,b12) KSTEP(1,b13) KSTEP(2,b14)  KSTEP(3,b15)  KSTEP(4,b16)  KSTEP(5,b17)
      KSTEP(6,b18) KSTEP(7,b19) KSTEP(8,b20)  KSTEP(9,b21)  KSTEP(10,b22) KSTEP(11,b23)
#undef KSTEP
    }

    const int m0c = row0 + chunk * 32;
    // ---- waves 2/3: export im panel to LDS; waves 4/5: store Du columns
    if (w == 2 || w == 3) {
      #pragma unroll
      for (int reg = 0; reg < 16; ++reg) {
        const int row = (reg & 3) + 8 * (reg >> 2) + 4 * kh;
        ldsim[w - 2][row][c] = acc[reg];
      }
    } else if (w >= 4) {
      #pragma unroll
      for (int reg = 0; reg < 16; ++reg) {
        const int row = (reg & 3) + 8 * (reg >> 2) + 4 * kh;
        Z[(size_t)(m0c + row) * WN + 128 + (w - 4) * 32 + c] = f2bf(acc[reg]);
      }
    }
    // lgkm-only barrier: keep next tile's global_load_lds in flight across the scan
    asm volatile("s_waitcnt lgkmcnt(0)\n\ts_barrier" ::: "memory");

    // ---- waves 0/1: in-register scan over the 32 rows (h = w*32 + c), store pairs + E
    if (w < 2) {
      float sr = 0.f, si = 0.f;
      #pragma unroll
      for (int g = 0; g < 8; ++g) {
        const int active = (g & 1);
        if (kh == active) {
          #pragma unroll
          for (int j = 0; j < 4; ++j) {
            const int rg = 4 * (g >> 1) + j;
            const int row = 4 * g + j;
            float im_in = ldsim[w][row][c];
            float nr = lr * sr - li * si + acc[rg];
            si = lr * si + li * sr + im_in;
            sr = nr;
            *(unsigned*)(Z + (size_t)(m0c + row) * WN + w * 64 + 2 * c) = pack2(sr, si);
          }
        }
        float tr = __shfl_xor(sr, 32), ti = __shfl_xor(si, 32);
        if (kh != active) { sr = tr; si = ti; }
      }
      if (kh == 0) {
        float* Ep = E + (size_t)(blockIdx.x * 4 + chunk) * 128;
        Ep[w * 32 + c] = sr;
        Ep[64 + w * 32 + c] = si;
      }
    }
  }
#undef ISSUE
}

// ---- K4: carry + correction + MFMA projection + Du + chunk max (no barriers) ----
__global__ __launch_bounds__(256, 4) void k4_scanproj(const short* __restrict__ Z,
                                                      const float* __restrict__ lamtab,
                                                      const float* __restrict__ E,
                                                      const short* __restrict__ Ctp,
                                                      float* __restrict__ P) {
  const int t = threadIdx.x, w = t >> 6, lane = t & 63;
  const int b = blockIdx.x >> 4, cg = blockIdx.x & 15;
  const int c = cg * 4 + w;                      // this wave's chunk
  __shared__ short xsA[4][CS * 128];             // 32 KB, swizzled A-frag layout
  const size_t zrow0 = (size_t)(b * L_ + c * CS) * WN;

  // carry over previous chunks (lane = h)
  const int h = lane;
  const float Lr = lamtab[128 + h], Li = lamtab[192 + h];
  const float lr = lamtab[h],       li = lamtab[64 + h];
  float cr = 0.f, ci = 0.f;
  const float* Eb = E + (size_t)b * NC * 128;
  for (int cp = 0; cp < c; ++cp) {
    float er = Eb[cp * 128 + h], ei = Eb[cp * 128 + 64 + h];
    float nr = Lr * cr - Li * ci + er;
    ci = Lr * ci + Li * cr + ei;
    cr = nr;
  }
  // correction: xs[l][h] = loc[l][h] + lam^{l+1} * carry ; write bf16 A-frag LDS
  {
    float wr2 = cr, wi2 = ci;
    short* xa = &xsA[w][0];
    const int ure = h >> 3, uim = 8 + (h >> 3), ho = h & 7;
    #pragma unroll 8
    for (int l = 0; l < CS; ++l) {
      float nr = lr * wr2 - li * wi2;
      wi2 = lr * wi2 + li * wr2;
      wr2 = nr;
      unsigned pr = *(const unsigned*)(Z + zrow0 + (size_t)l * WN + 2 * h);
      float xr = bf2f((short)(pr & 0xffff)) + wr2;
      float xi = bf2f((short)(pr >> 16))    + wi2;
      int l7 = l & 7;
      xa[l * 128 + ((ure & ~7) | ((ure ^ l7) & 7)) * 8 + ho] = f2bf(xr);
      xa[l * 128 + ((uim & ~7) | ((uim ^ l7) & 7)) * 8 + ho] = f2bf(xi);
    }
  }

  // MFMA projection: y(32x64) = [xs_re|xs_im](32x128) @ Ctp(128x64)
  const int cc = lane & 31, kh = lane >> 5;
  f32x16 y0, y1;
  #pragma unroll
  for (int j = 0; j < 16; ++j) { y0[j] = 0.f; y1[j] = 0.f; }
  #pragma unroll
  for (int ks = 0; ks < 8; ++ks) {
    int u = ks * 2 + kh;
    int up = (u & ~7) | ((u ^ (cc & 7)) & 7);
    short8 af = *(const short8*)&xsA[w][cc * 128 + up * 8];
    short8 g0 = *(const short8*)(Ctp + ((size_t)((0 * 8 + ks) * 64 + lane)) * 8);
    short8 g1 = *(const short8*)(Ctp + ((size_t)((1 * 8 + ks) * 64 + lane)) * 8);
    y0 = __builtin_amdgcn_mfma_f32_32x32x16_bf16(af, g0, y0, 0, 0, 0);
    y1 = __builtin_amdgcn_mfma_f32_32x32x16_bf16(af, g1, y1, 0, 0, 0);
  }
  // Du add + max over rows
  float mv0 = -3.4e38f, mv1 = -3.4e38f;
  #pragma unroll
  for (int reg = 0; reg < 16; ++reg) {
    const int row = (reg & 3) + 8 * (reg >> 2) + 4 * kh;
    float d0 = bf2f(Z[zrow0 + (size_t)row * WN + 128 + cc]);
    float d1 = bf2f(Z[zrow0 + (size_t)row * WN + 160 + cc]);
    mv0 = fmaxf(mv0, y0[reg] + d0);
    mv1 = fmaxf(mv1, y1[reg] + d1);
  }
  mv0 = fmaxf(mv0, __shfl_xor(mv0, 32));
  mv1 = fmaxf(mv1, __shfl_xor(mv1, 32));
  if (kh == 0) {
    float* Pp = P + ((size_t)b * NC + c) * 64;
    Pp[cc] = mv0;
    Pp[32 + cc] = mv1;
  }
}

// ---------------- K5: max over chunks ----------------
__global__ void k5_reduce(const float* __restrict__ P, float* __restrict__ out) {
  int idx = blockIdx.x * 256 + threadIdx.x;      // = b*64 + o
  int b = idx >> 6, o = idx & 63;
  float m = -3.4e38f;
  for (int c = 0; c < NC; ++c) m = fmaxf(m, P[((size_t)b * NC + c) * 64 + o]);
  out[idx] = m;
}

extern "C" void kernel_launch(void* const* d_in, const int* in_sizes, int n_in,
                              void* d_out, int out_size, void* d_ws, size_t ws_size,
                              hipStream_t stream) {
  const float* X         = (const float*)d_in[0];
  const float* nu_log    = (const float*)d_in[1];
  const float* theta_log = (const float*)d_in[2];
  const float* gamma_log = (const float*)d_in[3];
  const float* B_re      = (const float*)d_in[4];
  const float* B_im      = (const float*)d_in[5];
  const float* C_re      = (const float*)d_in[6];
  const float* C_im      = (const float*)d_in[7];
  const float* Dm        = (const float*)d_in[8];
  float* out = (float*)d_out;

  char* ws = (char*)d_ws;
  short* Wp     = (short*)ws;                       // 147456 B
  short* Ctp    = (short*)(ws + 147456);            // 16384 B
  float* lamtab = (float*)(ws + 163840);            // 1024 B
  short* Z      = (short*)(ws + 165888);            // 25165824 B
  float* E      = (float*)(ws + 165888 + 25165824); // 1048576 B
  float* P      = (float*)(ws + 165888 + 25165824 + 1048576); // 524288 B

  k0_prep<<<64, 256, 0, stream>>>(nu_log, theta_log, gamma_log, B_re, B_im,
                                  C_re, C_im, Dm, Wp, Ctp, lamtab);
  k1_gemm_scan<<<512, 384, 0, stream>>>(X, Wp, lamtab, Z, E);
  k4_scanproj<<<512, 256, 0, stream>>>(Z, lamtab, E, Ctp, P);
  k5_reduce<<<8, 256, 0, stream>>>(P, out);
}